// Round 3
// baseline (84.399 us; speedup 1.0000x reference)
//
#include <hip/hip_runtime.h>
#include <cstdint>
#include <cstddef>

__device__ static const int   d_GOV[66] = {
  21,21, 9,12, 9,12,17,17,17,17,15,16,15,16, 8, 8,11, 8,14, 7,14, 7,
  13,13,13,13,15,15,15,15,10,10,10,10, 4, 3, 4, 3, 1, 1, 1, 1, 6, 6,
   6, 6,18,18,18,18, 0,20, 0,20,16,16,16,16, 0, 2,19, 2,10, 5,10, 5};
__device__ static const float d_NSYN[66] = {
  0,0, 2,2,2,2, 4,4,4,4, 6,6,6,6, 3,3,1,3, 2,2,2,2, 4,4,4,4,
  6,6,6,6, 6,6,6,6, 2,2,2,2, 4,4,4,4, 4,4,4,4, 4,4,4,4,
  3,2,3,2, 6,6,6,6, 3,2,1,2, 6,2,6,2};

// Kernel 1: one thread per position; stream the 66-logit row into registers.
// Grid: B*L/256 blocks x 256 threads. No big LDS, no staging barrier.
__global__ __launch_bounds__(256, 4) void k_pos(
    const float* __restrict__ logits,
    const float* __restrict__ W,
    const int* __restrict__ tgt,
    const int* __restrict__ species,
    const unsigned char* __restrict__ mask,
    float* __restrict__ ws,
    int B, int L)
{
  const int tid  = threadIdx.x;
  const int lane = tid & 63;
  const int bpr  = L >> 8;                    // blocks per row (L multiple of 256)
  const int b    = blockIdx.x / bpr;
  const int pos  = blockIdx.x * 256 + tid;

  __shared__ int   s_cnt[132];                // [0..65]=pred, [66..131]=tgt
  __shared__ float s_acc[5];
  if (tid < 132) s_cnt[tid] = 0;
  if (tid < 5)   s_acc[tid] = 0.0f;

  // Stream row into registers: 33 x float2, static indices only.
  const float2* p2 = reinterpret_cast<const float2*>(logits + (size_t)pos * 66);
  float v[66];
  #pragma unroll
  for (int k = 0; k < 33; ++k) {
    float2 t = p2[k];
    v[2 * k] = t.x; v[2 * k + 1] = t.y;
  }
  const int   tg   = tgt[pos];
  const float mval = mask[pos] ? 1.0f : 0.0f;
  const int   s    = species[b];              // wave-uniform

  // argmax, two chains (chain0 = lower indices; strict > keeps first-index tie-break)
  float m0 = v[0]; int p0 = 0;
  #pragma unroll
  for (int k = 1; k < 33; ++k) { if (v[k] > m0) { m0 = v[k]; p0 = k; } }
  float m1 = v[33]; int p1 = 33;
  #pragma unroll
  for (int k = 34; k < 66; ++k) { if (v[k] > m1) { m1 = v[k]; p1 = k; } }
  float mx = m0; int pr = p0;
  if (m1 > m0) { mx = m1; pr = p1; }

  // sum of exps, 4 accumulators for ILP
  float se0 = 0.f, se1 = 0.f, se2 = 0.f, se3 = 0.f;
  #pragma unroll
  for (int k = 0; k < 64; k += 4) {
    se0 += __expf(v[k]     - mx);
    se1 += __expf(v[k + 1] - mx);
    se2 += __expf(v[k + 2] - mx);
    se3 += __expf(v[k + 3] - mx);
  }
  se0 += __expf(v[64] - mx);
  se1 += __expf(v[65] - mx);
  const float se = (se0 + se1) + (se2 + se3);

  // x[tgt] via select chain (registers stay registers; no scratch, no gather)
  float xt = v[0];
  #pragma unroll
  for (int k = 1; k < 66; ++k) xt = (tg == k) ? v[k] : xt;

  const float nll  = __logf(se) + mx - xt;
  const float ce_n = (tg != 0) ? nll : 0.0f;
  const float ce_d = (tg != 0) ? 1.0f : 0.0f;
  const float lw_p = __logf(fmaxf(W[s * 66 + pr], 1e-8f)) * mval;  // L1-hot gather
  const float lw_t = __logf(fmaxf(W[s * 66 + tg], 1e-8f)) * mval;

  __syncthreads();   // s_cnt/s_acc init visible
  if (mval != 0.0f) {
    if (pr >= 2) atomicAdd(&s_cnt[pr], 1);
    if (tg >= 2) atomicAdd(&s_cnt[66 + tg], 1);
  }

  float r0 = ce_n, r1 = ce_d, r2 = lw_p, r3 = lw_t, r4 = mval;
  #pragma unroll
  for (int off = 32; off > 0; off >>= 1) {
    r0 += __shfl_xor(r0, off);
    r1 += __shfl_xor(r1, off);
    r2 += __shfl_xor(r2, off);
    r3 += __shfl_xor(r3, off);
    r4 += __shfl_xor(r4, off);
  }
  if (lane == 0) {
    atomicAdd(&s_acc[0], r0);
    atomicAdd(&s_acc[1], r1);
    atomicAdd(&s_acc[2], r2);
    atomicAdd(&s_acc[3], r3);
    atomicAdd(&s_acc[4], r4);
  }
  __syncthreads();

  int* wsi = (int*)ws;
  const int off_slp = 2, off_slt = 2 + B, off_mc = 2 + 2 * B, off_cp = 2 + 3 * B;
  const int off_ct = off_cp + B * 66;
  if (tid == 0) {
    atomicAdd(&ws[0], s_acc[0]);
    atomicAdd(&ws[1], s_acc[1]);
    atomicAdd(&ws[off_slp + b], s_acc[2]);
    atomicAdd(&ws[off_slt + b], s_acc[3]);
    atomicAdd(&ws[off_mc + b], s_acc[4]);
  }
  if (tid < 66)       atomicAdd(&wsi[off_cp + b * 66 + tid], s_cnt[tid]);
  else if (tid < 132) atomicAdd(&wsi[off_ct + b * 66 + (tid - 66)], s_cnt[tid]);
}

// Kernel 2: per-row CAI + RSCU-KL, codon-parallel. Grid: B blocks x 128 threads.
__global__ __launch_bounds__(128) void k_row(
    const float* __restrict__ refd,
    const int* __restrict__ species,
    float* __restrict__ ws,
    int B)
{
  const int b    = blockIdx.x;
  const int tid  = threadIdx.x;
  const int lane = tid & 63;
  const int wave = tid >> 6;
  const int off_slp = 2, off_slt = 2 + B, off_mc = 2 + 2 * B, off_cp = 2 + 3 * B;
  const int off_ct = off_cp + B * 66;
  const int off_res = off_ct + B * 66;
  const int* wsi = (const int*)ws;

  __shared__ float gp[24], gt[24];
  __shared__ float red[8];
  if (tid < 24) { gp[tid] = 0.0f; gt[tid] = 0.0f; }
  __syncthreads();

  float cp = 0.0f, ct = 0.0f, nsyn = 0.0f, ref = 0.0f;
  int gov = 22;
  if (tid < 66) {
    cp = (float)wsi[off_cp + b * 66 + tid];
    ct = (float)wsi[off_ct + b * 66 + tid];
    gov  = d_GOV[tid];
    nsyn = d_NSYN[tid];
    ref  = refd[species[b] * 66 + tid];
    atomicAdd(&gp[gov], cp);   // integer-valued floats: order-independent exact
    atomicAdd(&gt[gov], ct);
  }
  __syncthreads();

  float rp = 0.0f, rt = 0.0f;
  if (tid < 66) {
    float g1 = gp[gov]; rp = (g1 > 0.0f) ? cp * nsyn / g1 : 0.0f;
    float g2 = gt[gov]; rt = (g2 > 0.0f) ? ct * nsyn / g2 : 0.0f;
  }
  float pp = (tid < 66) ? (rp + 1e-8f) : 0.0f;
  float tp = (tid < 66) ? (0.7f * rt + 0.3f * ref + 1e-8f) : 0.0f;
  #pragma unroll
  for (int off = 32; off > 0; off >>= 1) {
    pp += __shfl_xor(pp, off);
    tp += __shfl_xor(tp, off);
  }
  if (lane == 0) { red[wave * 2] = pp; red[wave * 2 + 1] = tp; }
  __syncthreads();
  const float psum = red[0] + red[2];
  const float tsum = red[1] + red[3];

  float kl = 0.0f;
  if (tid < 66) {
    float pv = (rp + 1e-8f) / psum;
    float tv = (0.7f * rt + 0.3f * ref + 1e-8f) / tsum;
    kl = tv * __logf(tv / pv);
  }
  #pragma unroll
  for (int off = 32; off > 0; off >>= 1) kl += __shfl_xor(kl, off);
  if (lane == 0) red[4 + wave] = kl;
  __syncthreads();

  if (tid == 0) {
    float klt = red[4] + red[5];
    float mc    = fmaxf(ws[off_mc + b], 1.0f);
    float cai_p = __expf(ws[off_slp + b] / mc);
    float cai_t = __expf(ws[off_slt + b] / mc);
    float cai_l = fmaxf(cai_t - cai_p, 0.0f);
    ws[off_res + b] = 0.4f * cai_l + 0.3f * klt;
  }
}

// Kernel 3: final scalar. 1 block, B threads.
__global__ __launch_bounds__(128) void k_sum(
    const float* __restrict__ ws,
    float* __restrict__ out, int B)
{
  const int b = threadIdx.x;
  const int lane = b & 63, wave = b >> 6;
  const int off_res = 2 + 3 * B + 2 * B * 66;
  float r = (b < B) ? ws[off_res + b] : 0.0f;
  #pragma unroll
  for (int off = 32; off > 0; off >>= 1) r += __shfl_xor(r, off);
  __shared__ float sr[2];
  if (lane == 0) sr[wave] = r;
  __syncthreads();
  if (b == 0) {
    float ce = ws[0] / fmaxf(ws[1], 1.0f);
    out[0] = ce + (sr[0] + sr[1]) / (float)B;
  }
}

extern "C" void kernel_launch(void* const* d_in, const int* in_sizes, int n_in,
                              void* d_out, int out_size, void* d_ws, size_t ws_size,
                              hipStream_t stream) {
  const float* logits  = (const float*)d_in[0];
  const float* W       = (const float*)d_in[1];
  const float* refd    = (const float*)d_in[2];
  const int*   tgt     = (const int*)d_in[3];
  // d_in[4] = aa_ids: unused by the reference
  const int*   species = (const int*)d_in[5];
  const unsigned char* mask = (const unsigned char*)d_in[6];  // numpy bool = 1 byte
  float* out = (float*)d_out;
  float* ws  = (float*)d_ws;

  const int B = in_sizes[5];
  const int L = in_sizes[3] / B;       // 4096
  const int nblk = (B * L) >> 8;       // one thread per position

  const int ws_words = 2 + 3 * B + 2 * B * 66 + B;
  hipMemsetAsync(d_ws, 0, (size_t)ws_words * 4, stream);

  hipLaunchKernelGGL(k_pos, dim3(nblk), dim3(256), 0, stream,
                     logits, W, tgt, species, mask, ws, B, L);
  hipLaunchKernelGGL(k_row, dim3(B), dim3(128), 0, stream,
                     refd, species, ws, B);
  hipLaunchKernelGGL(k_sum, dim3(1), dim3(128), 0, stream,
                     ws, out, B);
}